// Round 9
// baseline (130.566 us; speedup 1.0000x reference)
//
#include <hip/hip_runtime.h>
#include <hip/hip_bf16.h>
#include <math.h>

// out[b,i,p] = sqrt(yr^2+yi^2); yr/yi = (Hr/Hi[b] @ x[b])*scale + noise*0.01
// B=32, C=256, P=3136. Memory-bound (~290MB HBM -> ~47us floor).
// Round-9 = round-6 skeleton (H pre-permuted bf16, dense DMA staging, depth-2
// __syncthreads pipeline, verified swizzles) with BM=128 -> 256 (full M):
//   - per-iter wave work 2x (16 MFMA): staging slack now covers L2 latency
//   - blocks halve (1568): per-CU barrier/epilogue exposure halves
//   - x tile staged ONCE per (b,bn) (was 2x): ~50MB less read traffic
//   - 1568 = 8 XCDs x 196 (4 whole batches) exact bijection

#define NBATCH 32
#define NC 256
#define NP 3136
#define BM 256
#define BN 64
#define BK 32
#define NBN 49
#define NKI 8          // 256/32 K-steps

typedef __attribute__((ext_vector_type(8))) short short8;
typedef __attribute__((ext_vector_type(4))) float f32x4;

static __device__ __forceinline__ void gload16(const void* g, void* l) {
  __builtin_amdgcn_global_load_lds(
      (const __attribute__((address_space(1))) void*)g,
      (__attribute__((address_space(3))) void*)l, 16, 0, 0);
}

static __device__ __forceinline__ unsigned short bfr(float f) {
  __hip_bfloat16 h = __float2bfloat16(f);   // RNE; pairs into v_cvt_pk_bf16_f32
  return *reinterpret_cast<unsigned short*>(&h);
}

// ---- pre-pass: permute Hr/Hi fp32 -> bf16 ws in LDS-image layout ----
// ws elem idx: (((b2m*8 + kt)*2 + plane)*4096) + fq*1024 + (half*64+lane)*8 + e
//   b2m=b*2+bm128 (bm128 = 128-row slab), kt=K-tile, plane 0=r/1=i, fq=k-chunk.
__global__ __launch_bounds__(256)
void perm_h_kernel(const float* __restrict__ hr, const float* __restrict__ hi,
                   unsigned short* __restrict__ ws)
{
  const int blk   = blockIdx.x;        // b2m*8 + kt  (512 blocks)
  const int kt    = blk & 7;
  const int b2m   = blk >> 3;
  const int plane = threadIdx.x >> 7;  // 0..1
  const int row   = threadIdx.x & 127; // 0..127
  const int b     = b2m >> 1;
  const int bm    = b2m & 1;

  const float* src = (plane ? hi : hr)
      + ((size_t)b * NC + bm * 128 + row) * NC + kt * 32;
  unsigned short* dst = ws + ((size_t)(b2m * 8 + kt) * 2 + plane) * 4096 + row * 8;

  #pragma unroll
  for (int fq = 0; fq < 4; ++fq) {
    const float4 v0 = *reinterpret_cast<const float4*>(src + fq * 8);
    const float4 v1 = *reinterpret_cast<const float4*>(src + fq * 8 + 4);
    union { uint4 v; unsigned short u[8]; } o;
    o.u[0] = bfr(v0.x); o.u[1] = bfr(v0.y); o.u[2] = bfr(v0.z); o.u[3] = bfr(v0.w);
    o.u[4] = bfr(v1.x); o.u[5] = bfr(v1.y); o.u[6] = bfr(v1.z); o.u[7] = bfr(v1.w);
    *reinterpret_cast<uint4*>(dst + fq * 1024) = o.v;
  }
}

// x LDS: fp32 [k 0..31][p 0..63] per buffer, phys 16B-chunk = logical ^
// swz(k>>3) (0 bank conflicts, verified r2-r8). H LDS: bf16 [fq][row 0..255][8]
// (16-lane groups span 16 rows = 256B per fq -> 2-way = free).
template<int PRE>
__global__ __launch_bounds__(512, 4)
void rayleigh_main(const float* __restrict__ xg,
                   const float* __restrict__ Hrg,
                   const float* __restrict__ Hig,
                   const unsigned short* __restrict__ Hperm,
                   const float* __restrict__ nrg,
                   const float* __restrict__ nig,
                   float* __restrict__ outg)
{
  __shared__ float x_lds[2][BK * BN];            // 2 x 8KB
  __shared__ unsigned short hr_lds[2][8192];     // 2 x 16KB  [fq][row 0..255][8]
  __shared__ unsigned short hi_lds[2][8192];     // 2 x 16KB

  // XCD bijection: 1568 = 8*196; each XCD owns 4 whole batches.
  const int raw = blockIdx.x;
  const int v   = (raw & 7) * 196 + (raw >> 3);
  const int b   = v / NBN;
  const int bn  = v - b * NBN;

  const int tid  = threadIdx.x;
  const int lane = tid & 63;
  const int wave = tid >> 6;      // 8 waves: 4(M) x 2(N)
  const int wm   = wave >> 1;     // 0..3 (64 rows each)
  const int wn   = wave & 1;      // 0..1 (32 cols each)
  const int fr   = lane & 15;
  const int fq   = lane >> 4;

  const float* xsrc = xg + (size_t)b * NC * NP + (size_t)bn * BN;
  const size_t hrowbase = (size_t)b * NC;            // full 256-row M tile
  const size_t hpb      = (size_t)(b * 2) * 8;       // + bm2*8 + t

  // stage one K-tile into buffer `buf`: x 8KB (wave w -> chunk w) + H 32KB
  // (wave w -> 4 contiguous 1KB chunks from permuted ws). 5 vmem ops/wave.
  auto stage = [&](int t, int buf) {
    {
      const int C16 = wave * 64 + lane;          // 16B chunk idx in 8KB x-tile
      const int k   = C16 >> 4;
      const int cp  = C16 & 15;
      const int fqk = k >> 3;
      const int cl  = cp ^ (((fqk & 1) << 2) | (fqk >> 1));
      const float* src = xsrc + (size_t)(t * BK + k) * NP + cl * 4;
      gload16(src, (char*)x_lds[buf] + wave * 1024);
    }
    if constexpr (PRE) {
      #pragma unroll
      for (int i = 0; i < 4; ++i) {
        const int c     = wave * 4 + i;          // 0..31
        const int plane = c >> 4;                // 0=r, 1=i
        const int c4    = c & 15;
        const int bm2   = c4 >> 3;               // 128-row slab
        const int fqc   = (c4 >> 1) & 3;
        const int half  = c4 & 1;
        unsigned short* hl = plane ? hi_lds[buf] : hr_lds[buf];
        const unsigned short* src = Hperm
            + (((hpb + bm2 * 8 + t) * 2) + plane) * 4096
            + fqc * 1024 + (half * 64 + lane) * 8;   // contiguous per lane
        // dest: [fq][row][8] bytes = fqc*4096 + (bm2*128+half*64)*16 (+lane*16)
        gload16(src, (char*)hl + fqc * 4096 + bm2 * 2048 + half * 1024);
      }
    }
  };

  f32x4 accR[4][2], accI[4][2];
  #pragma unroll
  for (int m = 0; m < 4; ++m)
    #pragma unroll
    for (int n = 0; n < 2; ++n) {
      accR[m][n] = (f32x4){0.f, 0.f, 0.f, 0.f};
      accI[m][n] = (f32x4){0.f, 0.f, 0.f, 0.f};
    }

  const int xork = ((fq & 1) << 6) | ((fq >> 1) << 4);

  stage(0, 0);

  #pragma unroll
  for (int t = 0; t < NKI; ++t) {
    __syncthreads();                       // buffers[t&1] ready (drains DMA)
    if (t + 1 < NKI) stage(t + 1, (t + 1) & 1);

    // B-fragments (2 per wave): 16 swizzled ds_read_b32 + pk-convert
    const char* xbuf = (const char*)x_lds[t & 1];
    short8 xb[2];
    #pragma unroll
    for (int n = 0; n < 2; ++n) {
      const int pcol = ((wn * 32 + n * 16 + fr) << 2) ^ xork;
      union { short8 s; unsigned short u[8]; } u;
      #pragma unroll
      for (int j = 0; j < 8; ++j) {
        const float f = *reinterpret_cast<const float*>(xbuf + ((fq * 8 + j) << 8) + pcol);
        u.u[j] = bfr(f);
      }
      xb[n] = u.s;
    }

    // A-fragments from LDS (ds_read_b128, 2-way = free) + 16 MFMA
    #pragma unroll
    for (int m = 0; m < 4; ++m) {
      const int row = wm * 64 + m * 16 + fr;
      short8 ar, ai;
      if constexpr (PRE) {
        ar = *reinterpret_cast<const short8*>(&hr_lds[t & 1][fq * 2048 + row * 8]);
        ai = *reinterpret_cast<const short8*>(&hi_lds[t & 1][fq * 2048 + row * 8]);
      } else {
        const float* p1 = Hrg + (hrowbase + row) * NC + t * 32 + fq * 8;
        const float* p2 = Hig + (hrowbase + row) * NC + t * 32 + fq * 8;
        const float4 v0 = *reinterpret_cast<const float4*>(p1);
        const float4 v1 = *reinterpret_cast<const float4*>(p1 + 4);
        const float4 w0 = *reinterpret_cast<const float4*>(p2);
        const float4 w1 = *reinterpret_cast<const float4*>(p2 + 4);
        union { short8 s; unsigned short uu[8]; } a1, a2;
        a1.uu[0] = bfr(v0.x); a1.uu[1] = bfr(v0.y); a1.uu[2] = bfr(v0.z); a1.uu[3] = bfr(v0.w);
        a1.uu[4] = bfr(v1.x); a1.uu[5] = bfr(v1.y); a1.uu[6] = bfr(v1.z); a1.uu[7] = bfr(v1.w);
        a2.uu[0] = bfr(w0.x); a2.uu[1] = bfr(w0.y); a2.uu[2] = bfr(w0.z); a2.uu[3] = bfr(w0.w);
        a2.uu[4] = bfr(w1.x); a2.uu[5] = bfr(w1.y); a2.uu[6] = bfr(w1.z); a2.uu[7] = bfr(w1.w);
        ar = a1.s; ai = a2.s;
      }
      #pragma unroll
      for (int n = 0; n < 2; ++n) {
        accR[m][n] = __builtin_amdgcn_mfma_f32_16x16x32_bf16(ar, xb[n], accR[m][n], 0, 0, 0);
        accI[m][n] = __builtin_amdgcn_mfma_f32_16x16x32_bf16(ai, xb[n], accI[m][n], 0, 0, 0);
      }
    }
  }

  // ---- epilogue: noise + magnitude + NT store, streamed per (m,n) frag to
  //      bound VGPRs; desynced waves overlap this with other blocks' K-loops.
  const float scale = 0.04419417382415922f;  // 1/sqrt(512)
  const float nstd  = 0.01f;
  const size_t obase = ((size_t)b * NC + wm * 64 + fq * 4) * NP
                     + (size_t)bn * BN + wn * 32 + fr;
  #pragma unroll
  for (int m = 0; m < 4; ++m)
    #pragma unroll
    for (int n = 0; n < 2; ++n) {
      float nrv[4], niv[4];
      #pragma unroll
      for (int r = 0; r < 4; ++r) {
        const size_t idx = obase + (size_t)(m * 16 + r) * NP + n * 16;
        nrv[r] = nrg[idx];
        niv[r] = nig[idx];
      }
      #pragma unroll
      for (int r = 0; r < 4; ++r) {
        const size_t idx = obase + (size_t)(m * 16 + r) * NP + n * 16;
        const float yr = accR[m][n][r] * scale + nrv[r] * nstd;
        const float yi = accI[m][n][r] * scale + niv[r] * nstd;
        __builtin_nontemporal_store(sqrtf(yr * yr + yi * yi), outg + idx);
      }
    }
}

extern "C" void kernel_launch(void* const* d_in, const int* in_sizes, int n_in,
                              void* d_out, int out_size, void* d_ws, size_t ws_size,
                              hipStream_t stream) {
  const float* x  = (const float*)d_in[0];
  const float* Hr = (const float*)d_in[1];
  const float* Hi = (const float*)d_in[2];
  const float* nr = (const float*)d_in[3];
  const float* ni = (const float*)d_in[4];
  float* out = (float*)d_out;

  const size_t HN = (size_t)NBATCH * NC * NC;  // 2,097,152 elems per H array

  if (ws_size >= HN * 2 * sizeof(unsigned short)) {
    unsigned short* hperm = (unsigned short*)d_ws;
    hipLaunchKernelGGL(perm_h_kernel, dim3(512), dim3(256), 0, stream, Hr, Hi, hperm);
    hipLaunchKernelGGL((rayleigh_main<1>), dim3(NBATCH * NBN), dim3(512), 0, stream,
                       x, Hr, Hi, hperm, nr, ni, out);
  } else {
    hipLaunchKernelGGL((rayleigh_main<0>), dim3(NBATCH * NBN), dim3(512), 0, stream,
                       x, Hr, Hi, (const unsigned short*)nullptr, nr, ni, out);
  }
}

// Round 10
// 116.392 us; speedup vs baseline: 1.1218x; 1.1218x over previous
//
#include <hip/hip_runtime.h>
#include <hip/hip_bf16.h>
#include <math.h>

// out[b,i,p] = sqrt(yr^2+yi^2); yr/yi = (Hr/Hi[b] @ x[b])*scale + noise*0.01
// B=32, C=256, P=3136. Memory-bound (~290MB HBM -> ~47us floor).
// Round-10 = round-6 skeleton (best, 126us dispatch) + two coupled levers:
//  (1) TRANSPOSED MFMA: mfma(xb, h, acc) computes (Hx)^T with byte-identical
//      fragment registers -> D col=i(ch), row=p-quad -> each lane owns 4
//      CONSECUTIVE p -> noise loads + out stores become float4 (the 309MB
//      noise+out stream was scalar: 4x fewer instrs, 1KB/wave-instr).
//  (2) __launch_bounds__(512,6): 48KB LDS + low VGPR -> 3 blocks/CU,
//      occupancy 40% -> ~75% to hide the fat epilogue memory bursts.

#define NBATCH 32
#define NC 256
#define NP 3136
#define BM 128
#define BN 64
#define BK 32
#define NBN 49
#define NKI 8          // 256/32 K-steps

typedef __attribute__((ext_vector_type(8))) short short8;
typedef __attribute__((ext_vector_type(4))) float f32x4;

static __device__ __forceinline__ void gload16(const void* g, void* l) {
  __builtin_amdgcn_global_load_lds(
      (const __attribute__((address_space(1))) void*)g,
      (__attribute__((address_space(3))) void*)l, 16, 0, 0);
}

static __device__ __forceinline__ unsigned short bfr(float f) {
  __hip_bfloat16 h = __float2bfloat16(f);   // RNE; pairs into v_cvt_pk_bf16_f32
  return *reinterpret_cast<unsigned short*>(&h);
}

// ---- pre-pass: permute Hr/Hi fp32 -> bf16 ws in LDS-image layout ----
// ws elem idx: (((b2m*8 + kt)*2 + plane)*4096) + fq*1024 + row*8 + e
__global__ __launch_bounds__(256)
void perm_h_kernel(const float* __restrict__ hr, const float* __restrict__ hi,
                   unsigned short* __restrict__ ws)
{
  const int blk   = blockIdx.x;        // b2m*8 + kt  (512 blocks)
  const int kt    = blk & 7;
  const int b2m   = blk >> 3;
  const int plane = threadIdx.x >> 7;  // 0..1
  const int row   = threadIdx.x & 127; // 0..127
  const int b     = b2m >> 1;
  const int bm    = b2m & 1;

  const float* src = (plane ? hi : hr)
      + ((size_t)b * NC + bm * 128 + row) * NC + kt * 32;
  unsigned short* dst = ws + ((size_t)(b2m * 8 + kt) * 2 + plane) * 4096 + row * 8;

  #pragma unroll
  for (int fq = 0; fq < 4; ++fq) {
    const float4 v0 = *reinterpret_cast<const float4*>(src + fq * 8);
    const float4 v1 = *reinterpret_cast<const float4*>(src + fq * 8 + 4);
    union { uint4 v; unsigned short u[8]; } o;
    o.u[0] = bfr(v0.x); o.u[1] = bfr(v0.y); o.u[2] = bfr(v0.z); o.u[3] = bfr(v0.w);
    o.u[4] = bfr(v1.x); o.u[5] = bfr(v1.y); o.u[6] = bfr(v1.z); o.u[7] = bfr(v1.w);
    *reinterpret_cast<uint4*>(dst + fq * 1024) = o.v;
  }
}

// x LDS: fp32 [k 0..31][p 0..63] per buffer, phys 16B-chunk = logical ^
// swz(k>>3) (0 bank conflicts, verified r2-r9). H LDS: bf16 [fq][row][8]
// (2-way = free). Pipeline: depth-2, one __syncthreads per iter (R6, best).
// MFMA operand swap: A:=xb (row=p=fr, k=fq*8+j), B:=h (col=i=fr, same k) --
// identical register bytes as the verified r1-r9 fragments; D[p][i]:
// col=lane&15=i, row=(lane>>4)*4+r = p-quad -> acc[m][r] = out[i0+m*16+fr]
// [p0+fq*4+r]: r runs over CONSECUTIVE p -> float4 epilogue.
template<int PRE>
__global__ __launch_bounds__(512, 6)
void rayleigh_main(const float* __restrict__ xg,
                   const float* __restrict__ Hrg,
                   const float* __restrict__ Hig,
                   const unsigned short* __restrict__ Hperm,
                   const float* __restrict__ nrg,
                   const float* __restrict__ nig,
                   float* __restrict__ outg)
{
  __shared__ float x_lds[2][BK * BN];            // 2 x 8KB
  __shared__ unsigned short hr_lds[2][4096];     // 2 x 8KB  [fq][row][8]
  __shared__ unsigned short hi_lds[2][4096];     // 2 x 8KB

  // XCD-chunked bijection: 3136 = 8*392. Each XCD owns 4 whole batches.
  const int raw = blockIdx.x;
  const int v   = (raw & 7) * 392 + (raw >> 3);
  const int b   = v / 98;
  const int r2  = v - b * 98;
  const int bm  = r2 / 49;
  const int bn  = r2 - bm * 49;

  const int tid  = threadIdx.x;
  const int lane = tid & 63;
  const int wave = tid >> 6;      // 8 waves: 2(M) x 4(N)
  const int wm   = wave >> 2;
  const int wn   = wave & 3;
  const int fr   = lane & 15;
  const int fq   = lane >> 4;

  const float* xsrc = xg + (size_t)b * NC * NP + (size_t)bn * BN;
  const size_t hrowbase = (size_t)b * NC + bm * BM;
  const size_t hpbase   = (size_t)((b * 2 + bm) * 8);

  // stage one K-tile into buffer `buf`: x 8KB (wave w -> chunk w) + H 16KB
  // (wave w -> 2 contiguous 1KB chunks from permuted ws). 3 vmem ops/wave.
  auto stage = [&](int t, int buf) {
    {
      const int C16 = wave * 64 + lane;          // 16B chunk idx in 8KB x-tile
      const int k   = C16 >> 4;
      const int cp  = C16 & 15;
      const int fqk = k >> 3;
      const int cl  = cp ^ (((fqk & 1) << 2) | (fqk >> 1));
      const float* src = xsrc + (size_t)(t * BK + k) * NP + cl * 4;
      gload16(src, (char*)x_lds[buf] + wave * 1024);
    }
    if constexpr (PRE) {
      #pragma unroll
      for (int i = 0; i < 2; ++i) {
        const int c     = wave * 2 + i;          // 0..15
        const int plane = c >> 3;                // 0=r, 1=i
        const int fqc   = (c >> 1) & 3;
        const int half  = c & 1;
        unsigned short* hl = plane ? hi_lds[buf] : hr_lds[buf];
        const unsigned short* src = Hperm
            + ((hpbase + t) * 2 + plane) * 4096
            + fqc * 1024 + (half * 64 + lane) * 8;   // contiguous per lane
        gload16(src, (char*)hl + fqc * 2048 + half * 1024);
      }
    }
  };

  f32x4 accR[4], accI[4];
  #pragma unroll
  for (int m = 0; m < 4; ++m) {
    accR[m] = (f32x4){0.f, 0.f, 0.f, 0.f};
    accI[m] = (f32x4){0.f, 0.f, 0.f, 0.f};
  }

  const int xork = ((fq & 1) << 6) | ((fq >> 1) << 4);
  const int pcol = ((wn * 16 + fr) << 2) ^ xork;

  stage(0, 0);

  #pragma unroll
  for (int t = 0; t < NKI; ++t) {
    __syncthreads();                       // buffers[t&1] ready (drains DMA)
    if (t + 1 < NKI) stage(t + 1, (t + 1) & 1);

    // x A-fragment: 8 swizzled ds_read_b32 + pk-convert (0 bank conflicts)
    const char* xbuf = (const char*)x_lds[t & 1];
    union { short8 s; unsigned short u[8]; } u;
    #pragma unroll
    for (int j = 0; j < 8; ++j) {
      const float f = *reinterpret_cast<const float*>(xbuf + ((fq * 8 + j) << 8) + pcol);
      u.u[j] = bfr(f);
    }
    const short8 xb = u.s;

    // H B-fragments from LDS (ds_read_b128, 2-way = free) + TRANSPOSED MFMA
    #pragma unroll
    for (int m = 0; m < 4; ++m) {
      const int row = wm * 64 + m * 16 + fr;
      short8 ar, ai;
      if constexpr (PRE) {
        ar = *reinterpret_cast<const short8*>(&hr_lds[t & 1][fq * 1024 + row * 8]);
        ai = *reinterpret_cast<const short8*>(&hi_lds[t & 1][fq * 1024 + row * 8]);
      } else {
        const float* p1 = Hrg + (hrowbase + row) * NC + t * 32 + fq * 8;
        const float* p2 = Hig + (hrowbase + row) * NC + t * 32 + fq * 8;
        const float4 v0 = *reinterpret_cast<const float4*>(p1);
        const float4 v1 = *reinterpret_cast<const float4*>(p1 + 4);
        const float4 w0 = *reinterpret_cast<const float4*>(p2);
        const float4 w1 = *reinterpret_cast<const float4*>(p2 + 4);
        union { short8 s; unsigned short uu[8]; } a1, a2;
        a1.uu[0] = bfr(v0.x); a1.uu[1] = bfr(v0.y); a1.uu[2] = bfr(v0.z); a1.uu[3] = bfr(v0.w);
        a1.uu[4] = bfr(v1.x); a1.uu[5] = bfr(v1.y); a1.uu[6] = bfr(v1.z); a1.uu[7] = bfr(v1.w);
        a2.uu[0] = bfr(w0.x); a2.uu[1] = bfr(w0.y); a2.uu[2] = bfr(w0.z); a2.uu[3] = bfr(w0.w);
        a2.uu[4] = bfr(w1.x); a2.uu[5] = bfr(w1.y); a2.uu[6] = bfr(w1.z); a2.uu[7] = bfr(w1.w);
        ar = a1.s; ai = a2.s;
      }
      // operand swap: D = x^T * H^T = (H x)^T, register contents unchanged
      accR[m] = __builtin_amdgcn_mfma_f32_16x16x32_bf16(xb, ar, accR[m], 0, 0, 0);
      accI[m] = __builtin_amdgcn_mfma_f32_16x16x32_bf16(xb, ai, accI[m], 0, 0, 0);
    }
  }

  // ---- epilogue: float4 noise loads + magnitude + float4 stores ----
  // lane(fr,fq), frag m: out[i = bm*128+wm*64+m*16+fr][p = bn*64+wn*16+fq*4+r]
  // r=0..3 consecutive p -> one float4 per (m,array). 16B-aligned (all offsets
  // multiples of 4 floats; i*NP*4 = i*12544 % 16 == 0).
  const float scale = 0.04419417382415922f;  // 1/sqrt(512)
  const float nstd  = 0.01f;
  const size_t obase = ((size_t)b * NC + bm * BM + wm * 64 + fr) * NP
                     + (size_t)bn * BN + wn * 16 + fq * 4;
  #pragma unroll
  for (int m = 0; m < 4; ++m) {
    const size_t idx = obase + (size_t)(m * 16) * NP;
    const float4 nr4 = *reinterpret_cast<const float4*>(nrg + idx);
    const float4 ni4 = *reinterpret_cast<const float4*>(nig + idx);
    float4 o;
    {
      const float yr = accR[m][0] * scale + nr4.x * nstd;
      const float yi = accI[m][0] * scale + ni4.x * nstd;
      o.x = sqrtf(yr * yr + yi * yi);
    }
    {
      const float yr = accR[m][1] * scale + nr4.y * nstd;
      const float yi = accI[m][1] * scale + ni4.y * nstd;
      o.y = sqrtf(yr * yr + yi * yi);
    }
    {
      const float yr = accR[m][2] * scale + nr4.z * nstd;
      const float yi = accI[m][2] * scale + ni4.z * nstd;
      o.z = sqrtf(yr * yr + yi * yi);
    }
    {
      const float yr = accR[m][3] * scale + nr4.w * nstd;
      const float yi = accI[m][3] * scale + ni4.w * nstd;
      o.w = sqrtf(yr * yr + yi * yi);
    }
    *reinterpret_cast<float4*>(outg + idx) = o;
  }
}

extern "C" void kernel_launch(void* const* d_in, const int* in_sizes, int n_in,
                              void* d_out, int out_size, void* d_ws, size_t ws_size,
                              hipStream_t stream) {
  const float* x  = (const float*)d_in[0];
  const float* Hr = (const float*)d_in[1];
  const float* Hi = (const float*)d_in[2];
  const float* nr = (const float*)d_in[3];
  const float* ni = (const float*)d_in[4];
  float* out = (float*)d_out;

  const size_t HN = (size_t)NBATCH * NC * NC;  // 2,097,152 elems per H array

  if (ws_size >= HN * 2 * sizeof(unsigned short)) {
    unsigned short* hperm = (unsigned short*)d_ws;
    hipLaunchKernelGGL(perm_h_kernel, dim3(512), dim3(256), 0, stream, Hr, Hi, hperm);
    hipLaunchKernelGGL((rayleigh_main<1>), dim3(NBATCH * 2 * NBN), dim3(512), 0, stream,
                       x, Hr, Hi, hperm, nr, ni, out);
  } else {
    hipLaunchKernelGGL((rayleigh_main<0>), dim3(NBATCH * 2 * NBN), dim3(512), 0, stream,
                       x, Hr, Hi, (const unsigned short*)nullptr, nr, ni, out);
  }
}

// Round 11
// 115.261 us; speedup vs baseline: 1.1328x; 1.0098x over previous
//
#include <hip/hip_runtime.h>
#include <hip/hip_bf16.h>
#include <math.h>

// out[b,i,p] = sqrt(yr^2+yi^2); yr/yi = (Hr/Hi[b] @ x[b])*scale + noise*0.01
// B=32, C=256, P=3136. Memory-bound (~290MB HBM -> ~46us floor).
// Round-11: HBM demand SMOOTHING. Noise (206MB, 2/3 of traffic) loaded as one
// float4/iter INSIDE the K-loop (R6's spreading, R10's transposed-layout
// vectorization): HBM flows during the L2-bound GEMM phase instead of
// bursting in the epilogue (measured duty-cycle ~33% == observed 2.1-2.4TB/s).
// Transposed MFMA (validated r10): lane owns 4 consecutive p -> float4 IO.
// NT float4 out stores. 3 blocks/CU.

#define NBATCH 32
#define NC 256
#define NP 3136
#define BM 128
#define BN 64
#define BK 32
#define NBN 49
#define NKI 8          // 256/32 K-steps

typedef __attribute__((ext_vector_type(8))) short short8;
typedef __attribute__((ext_vector_type(4))) float f32x4;

static __device__ __forceinline__ void gload16(const void* g, void* l) {
  __builtin_amdgcn_global_load_lds(
      (const __attribute__((address_space(1))) void*)g,
      (__attribute__((address_space(3))) void*)l, 16, 0, 0);
}

static __device__ __forceinline__ unsigned short bfr(float f) {
  __hip_bfloat16 h = __float2bfloat16(f);   // RNE; pairs into v_cvt_pk_bf16_f32
  return *reinterpret_cast<unsigned short*>(&h);
}

// ---- pre-pass: permute Hr/Hi fp32 -> bf16 ws in LDS-image layout ----
// ws elem idx: (((b2m*8 + kt)*2 + plane)*4096) + fq*1024 + row*8 + e
__global__ __launch_bounds__(256)
void perm_h_kernel(const float* __restrict__ hr, const float* __restrict__ hi,
                   unsigned short* __restrict__ ws)
{
  const int blk   = blockIdx.x;        // b2m*8 + kt  (512 blocks)
  const int kt    = blk & 7;
  const int b2m   = blk >> 3;
  const int plane = threadIdx.x >> 7;  // 0..1
  const int row   = threadIdx.x & 127; // 0..127
  const int b     = b2m >> 1;
  const int bm    = b2m & 1;

  const float* src = (plane ? hi : hr)
      + ((size_t)b * NC + bm * 128 + row) * NC + kt * 32;
  unsigned short* dst = ws + ((size_t)(b2m * 8 + kt) * 2 + plane) * 4096 + row * 8;

  #pragma unroll
  for (int fq = 0; fq < 4; ++fq) {
    const float4 v0 = *reinterpret_cast<const float4*>(src + fq * 8);
    const float4 v1 = *reinterpret_cast<const float4*>(src + fq * 8 + 4);
    union { uint4 v; unsigned short u[8]; } o;
    o.u[0] = bfr(v0.x); o.u[1] = bfr(v0.y); o.u[2] = bfr(v0.z); o.u[3] = bfr(v0.w);
    o.u[4] = bfr(v1.x); o.u[5] = bfr(v1.y); o.u[6] = bfr(v1.z); o.u[7] = bfr(v1.w);
    *reinterpret_cast<uint4*>(dst + fq * 1024) = o.v;
  }
}

// x LDS: fp32 [k 0..31][p 0..63] per buffer, phys 16B-chunk = logical ^
// swz(k>>3) (0 bank conflicts, r2-r10). H LDS: bf16 [fq][row][8] (2-way free).
// Depth-2, one __syncthreads/iter (R6 structure, best). Transposed MFMA
// (r10-validated): D[p][i] -> acc[m][r] = out[i0+m*16+fr][p0+fq*4+r],
// r = consecutive p -> float4 noise/out IO.
template<int PRE>
__global__ __launch_bounds__(512, 6)
void rayleigh_main(const float* __restrict__ xg,
                   const float* __restrict__ Hrg,
                   const float* __restrict__ Hig,
                   const unsigned short* __restrict__ Hperm,
                   const float* __restrict__ nrg,
                   const float* __restrict__ nig,
                   float* __restrict__ outg)
{
  __shared__ float x_lds[2][BK * BN];            // 2 x 8KB
  __shared__ unsigned short hr_lds[2][4096];     // 2 x 8KB  [fq][row][8]
  __shared__ unsigned short hi_lds[2][4096];     // 2 x 8KB

  // XCD-chunked bijection: 3136 = 8*392. Each XCD owns 4 whole batches.
  const int raw = blockIdx.x;
  const int v   = (raw & 7) * 392 + (raw >> 3);
  const int b   = v / 98;
  const int r2  = v - b * 98;
  const int bm  = r2 / 49;
  const int bn  = r2 - bm * 49;

  const int tid  = threadIdx.x;
  const int lane = tid & 63;
  const int wave = tid >> 6;      // 8 waves: 2(M) x 4(N)
  const int wm   = wave >> 2;
  const int wn   = wave & 3;
  const int fr   = lane & 15;
  const int fq   = lane >> 4;

  const float* xsrc = xg + (size_t)b * NC * NP + (size_t)bn * BN;
  const size_t hpbase = (size_t)((b * 2 + bm) * 8);

  // stage one K-tile into buffer `buf`: x 8KB (wave w -> chunk w) + H 16KB
  // (wave w -> 2 contiguous 1KB chunks from permuted ws). 3 vmem ops/wave.
  auto stage = [&](int t, int buf) {
    {
      const int C16 = wave * 64 + lane;          // 16B chunk idx in 8KB x-tile
      const int k   = C16 >> 4;
      const int cp  = C16 & 15;
      const int fqk = k >> 3;
      const int cl  = cp ^ (((fqk & 1) << 2) | (fqk >> 1));
      const float* src = xsrc + (size_t)(t * BK + k) * NP + cl * 4;
      gload16(src, (char*)x_lds[buf] + wave * 1024);
    }
    #pragma unroll
    for (int i = 0; i < 2; ++i) {
      const int c     = wave * 2 + i;          // 0..15
      const int plane = c >> 3;                // 0=r, 1=i
      const int fqc   = (c >> 1) & 3;
      const int half  = c & 1;
      unsigned short* hl = plane ? hi_lds[buf] : hr_lds[buf];
      const unsigned short* src = Hperm
          + ((hpbase + t) * 2 + plane) * 4096
          + fqc * 1024 + (half * 64 + lane) * 8;   // contiguous per lane
      gload16(src, (char*)hl + fqc * 2048 + half * 1024);
    }
  };

  f32x4 accR[4], accI[4];
  #pragma unroll
  for (int m = 0; m < 4; ++m) {
    accR[m] = (f32x4){0.f, 0.f, 0.f, 0.f};
    accI[m] = (f32x4){0.f, 0.f, 0.f, 0.f};
  }

  const int xork = ((fq & 1) << 6) | ((fq >> 1) << 4);
  const int pcol = ((wn * 16 + fr) << 2) ^ xork;

  // transposed-layout output base: row i = bm*128+wm*64+fr (+m*16),
  // col p = bn*64+wn*16+fq*4 (+r). float4-aligned.
  const size_t obase = ((size_t)b * NC + bm * BM + wm * 64 + fr) * NP
                     + (size_t)bn * BN + wn * 16 + fq * 4;

  float4 nrv[4], niv[4];   // in-loop noise prefetch (32 VGPRs)

  stage(0, 0);

  #pragma unroll
  for (int t = 0; t < NKI; ++t) {
    __syncthreads();                       // buffers[t&1] ready (drains DMA)
    if (t + 1 < NKI) stage(t + 1, (t + 1) & 1);

    // noise chunk t: ONE float4/iter -> HBM flows during the L2-bound GEMM
    // phase (t even: nr[m=t/2]; t odd: ni[m=t/2]). Static index (unrolled).
    {
      const size_t nidx = obase + (size_t)((t >> 1) * 16) * NP;
      if ((t & 1) == 0) nrv[t >> 1] = *reinterpret_cast<const float4*>(nrg + nidx);
      else              niv[t >> 1] = *reinterpret_cast<const float4*>(nig + nidx);
    }

    // x A-fragment: 8 swizzled ds_read_b32 + pk-convert (0 bank conflicts)
    const char* xbuf = (const char*)x_lds[t & 1];
    union { short8 s; unsigned short u[8]; } u;
    #pragma unroll
    for (int j = 0; j < 8; ++j) {
      const float f = *reinterpret_cast<const float*>(xbuf + ((fq * 8 + j) << 8) + pcol);
      u.u[j] = bfr(f);
    }
    const short8 xb = u.s;

    // H B-fragments from LDS (ds_read_b128, 2-way = free) + transposed MFMA
    #pragma unroll
    for (int m = 0; m < 4; ++m) {
      const int row = wm * 64 + m * 16 + fr;
      const short8 ar = *reinterpret_cast<const short8*>(&hr_lds[t & 1][fq * 1024 + row * 8]);
      const short8 ai = *reinterpret_cast<const short8*>(&hi_lds[t & 1][fq * 1024 + row * 8]);
      accR[m] = __builtin_amdgcn_mfma_f32_16x16x32_bf16(xb, ar, accR[m], 0, 0, 0);
      accI[m] = __builtin_amdgcn_mfma_f32_16x16x32_bf16(xb, ai, accI[m], 0, 0, 0);
    }
  }

  // ---- epilogue: pure compute + NT float4 stores (noise already in regs) ----
  const float scale = 0.04419417382415922f;  // 1/sqrt(512)
  const float nstd  = 0.01f;
  #pragma unroll
  for (int m = 0; m < 4; ++m) {
    const size_t idx = obase + (size_t)(m * 16) * NP;
    float4 o;
    {
      const float yr = accR[m][0] * scale + nrv[m].x * nstd;
      const float yi = accI[m][0] * scale + niv[m].x * nstd;
      o.x = sqrtf(yr * yr + yi * yi);
    }
    {
      const float yr = accR[m][1] * scale + nrv[m].y * nstd;
      const float yi = accI[m][1] * scale + niv[m].y * nstd;
      o.y = sqrtf(yr * yr + yi * yi);
    }
    {
      const float yr = accR[m][2] * scale + nrv[m].z * nstd;
      const float yi = accI[m][2] * scale + niv[m].z * nstd;
      o.z = sqrtf(yr * yr + yi * yi);
    }
    {
      const float yr = accR[m][3] * scale + nrv[m].w * nstd;
      const float yi = accI[m][3] * scale + niv[m].w * nstd;
      o.w = sqrtf(yr * yr + yi * yi);
    }
    __builtin_nontemporal_store(o.x, outg + idx + 0);
    __builtin_nontemporal_store(o.y, outg + idx + 1);
    __builtin_nontemporal_store(o.z, outg + idx + 2);
    __builtin_nontemporal_store(o.w, outg + idx + 3);
  }
}

// fallback (no workspace): round-3-style self-contained path
__global__ __launch_bounds__(512, 4)
void rayleigh_fallback(const float* __restrict__ xg,
                       const float* __restrict__ Hrg,
                       const float* __restrict__ Hig,
                       const float* __restrict__ nrg,
                       const float* __restrict__ nig,
                       float* __restrict__ outg)
{
  __shared__ float x_lds[2][BK * BN];

  const int raw = blockIdx.x;
  const int v   = (raw & 7) * 392 + (raw >> 3);
  const int b   = v / 98;
  const int r2  = v - b * 98;
  const int bm  = r2 / 49;
  const int bn  = r2 - bm * 49;

  const int tid  = threadIdx.x;
  const int lane = tid & 63;
  const int wave = tid >> 6;
  const int wm   = wave >> 2;
  const int wn   = wave & 3;
  const int fr   = lane & 15;
  const int fq   = lane >> 4;

  const float* xsrc = xg + (size_t)b * NC * NP + (size_t)bn * BN;
  const size_t hrowbase = (size_t)b * NC + bm * BM;

  auto stage = [&](int t, int buf) {
    const int C16 = wave * 64 + lane;
    const int k   = C16 >> 4;
    const int cp  = C16 & 15;
    const int fqk = k >> 3;
    const int cl  = cp ^ (((fqk & 1) << 2) | (fqk >> 1));
    gload16(xsrc + (size_t)(t * BK + k) * NP + cl * 4, (char*)x_lds[buf] + wave * 1024);
  };

  f32x4 accR[4], accI[4];
  #pragma unroll
  for (int m = 0; m < 4; ++m) {
    accR[m] = (f32x4){0.f, 0.f, 0.f, 0.f};
    accI[m] = (f32x4){0.f, 0.f, 0.f, 0.f};
  }

  const int xork = ((fq & 1) << 6) | ((fq >> 1) << 4);
  const int pcol = ((wn * 16 + fr) << 2) ^ xork;

  stage(0, 0);
  for (int t = 0; t < NKI; ++t) {
    __syncthreads();
    if (t + 1 < NKI) stage(t + 1, (t + 1) & 1);
    const char* xbuf = (const char*)x_lds[t & 1];
    union { short8 s; unsigned short u[8]; } u;
    #pragma unroll
    for (int j = 0; j < 8; ++j) {
      const float f = *reinterpret_cast<const float*>(xbuf + ((fq * 8 + j) << 8) + pcol);
      u.u[j] = bfr(f);
    }
    const short8 xb = u.s;
    #pragma unroll
    for (int m = 0; m < 4; ++m) {
      const int row = wm * 64 + m * 16 + fr;
      const float* p1 = Hrg + (hrowbase + row) * NC + t * 32 + fq * 8;
      const float* p2 = Hig + (hrowbase + row) * NC + t * 32 + fq * 8;
      const float4 v0 = *reinterpret_cast<const float4*>(p1);
      const float4 v1 = *reinterpret_cast<const float4*>(p1 + 4);
      const float4 w0 = *reinterpret_cast<const float4*>(p2);
      const float4 w1 = *reinterpret_cast<const float4*>(p2 + 4);
      union { short8 s; unsigned short uu[8]; } a1, a2;
      a1.uu[0] = bfr(v0.x); a1.uu[1] = bfr(v0.y); a1.uu[2] = bfr(v0.z); a1.uu[3] = bfr(v0.w);
      a1.uu[4] = bfr(v1.x); a1.uu[5] = bfr(v1.y); a1.uu[6] = bfr(v1.z); a1.uu[7] = bfr(v1.w);
      a2.uu[0] = bfr(w0.x); a2.uu[1] = bfr(w0.y); a2.uu[2] = bfr(w0.z); a2.uu[3] = bfr(w0.w);
      a2.uu[4] = bfr(w1.x); a2.uu[5] = bfr(w1.y); a2.uu[6] = bfr(w1.z); a2.uu[7] = bfr(w1.w);
      accR[m] = __builtin_amdgcn_mfma_f32_16x16x32_bf16(xb, a1.s, accR[m], 0, 0, 0);
      accI[m] = __builtin_amdgcn_mfma_f32_16x16x32_bf16(xb, a2.s, accI[m], 0, 0, 0);
    }
  }

  const float scale = 0.04419417382415922f;
  const float nstd  = 0.01f;
  const size_t obase = ((size_t)b * NC + bm * BM + wm * 64 + fr) * NP
                     + (size_t)bn * BN + wn * 16 + fq * 4;
  #pragma unroll
  for (int m = 0; m < 4; ++m) {
    const size_t idx = obase + (size_t)(m * 16) * NP;
    const float4 nr4 = *reinterpret_cast<const float4*>(nrg + idx);
    const float4 ni4 = *reinterpret_cast<const float4*>(nig + idx);
    float4 o;
    o.x = sqrtf((accR[m][0]*scale + nr4.x*nstd)*(accR[m][0]*scale + nr4.x*nstd) +
                (accI[m][0]*scale + ni4.x*nstd)*(accI[m][0]*scale + ni4.x*nstd));
    o.y = sqrtf((accR[m][1]*scale + nr4.y*nstd)*(accR[m][1]*scale + nr4.y*nstd) +
                (accI[m][1]*scale + ni4.y*nstd)*(accI[m][1]*scale + ni4.y*nstd));
    o.z = sqrtf((accR[m][2]*scale + nr4.z*nstd)*(accR[m][2]*scale + nr4.z*nstd) +
                (accI[m][2]*scale + ni4.z*nstd)*(accI[m][2]*scale + ni4.z*nstd));
    o.w = sqrtf((accR[m][3]*scale + nr4.w*nstd)*(accR[m][3]*scale + nr4.w*nstd) +
                (accI[m][3]*scale + ni4.w*nstd)*(accI[m][3]*scale + ni4.w*nstd));
    *reinterpret_cast<float4*>(outg + idx) = o;
  }
}

extern "C" void kernel_launch(void* const* d_in, const int* in_sizes, int n_in,
                              void* d_out, int out_size, void* d_ws, size_t ws_size,
                              hipStream_t stream) {
  const float* x  = (const float*)d_in[0];
  const float* Hr = (const float*)d_in[1];
  const float* Hi = (const float*)d_in[2];
  const float* nr = (const float*)d_in[3];
  const float* ni = (const float*)d_in[4];
  float* out = (float*)d_out;

  const size_t HN = (size_t)NBATCH * NC * NC;  // 2,097,152 elems per H array

  if (ws_size >= HN * 2 * sizeof(unsigned short)) {
    unsigned short* hperm = (unsigned short*)d_ws;
    hipLaunchKernelGGL(perm_h_kernel, dim3(512), dim3(256), 0, stream, Hr, Hi, hperm);
    hipLaunchKernelGGL((rayleigh_main<1>), dim3(NBATCH * 2 * NBN), dim3(512), 0, stream,
                       x, Hr, Hi, hperm, nr, ni, out);
  } else {
    hipLaunchKernelGGL(rayleigh_fallback, dim3(NBATCH * 2 * NBN), dim3(512), 0, stream,
                       x, Hr, Hi, nr, ni, out);
  }
}

// Round 12
// 103.726 us; speedup vs baseline: 1.2588x; 1.1112x over previous
//
#include <hip/hip_runtime.h>
#include <hip/hip_bf16.h>
#include <math.h>

// out[b,i,p] = sqrt(yr^2+yi^2); yr/yi = (Hr/Hi[b] @ x[b])*scale + noise*0.01
// B=32, C=256, P=3136. Memory-bound (~290MB HBM -> ~47us floor).
// Round-12 = round-6 EXACT (best: dur 107, dispatch 126) + ONE lever:
// counted-vmcnt barrier. __syncthreads drained vmcnt(0) every iter, forcing
// the 4 in-flight NT noise loads (~900cy HBM latency, needed only in the
// epilogue) to retire 8x per block. vmcnt(4) retires exactly stage(t) (3
// oldest, L2-hot) and lets noise float to its epilogue use. (R5 tested this
// on the unpermuted-H base where 8x-amplified staging confounded it.)

#define NBATCH 32
#define NC 256
#define NP 3136
#define BM 128
#define BN 64
#define BK 32
#define NBN 49
#define NKI 8          // 256/32 K-steps

typedef __attribute__((ext_vector_type(8))) short short8;
typedef __attribute__((ext_vector_type(4))) float f32x4;

static __device__ __forceinline__ void gload16(const void* g, void* l) {
  __builtin_amdgcn_global_load_lds(
      (const __attribute__((address_space(1))) void*)g,
      (__attribute__((address_space(3))) void*)l, 16, 0, 0);
}

static __device__ __forceinline__ unsigned short bfr(float f) {
  __hip_bfloat16 h = __float2bfloat16(f);   // RNE; pairs into v_cvt_pk_bf16_f32
  return *reinterpret_cast<unsigned short*>(&h);
}

// ---- pre-pass: permute Hr/Hi fp32 -> bf16 ws in LDS-image layout ----
// ws elem idx: (((b2m*8 + kt)*2 + plane)*4096) + fq*1024 + row*8 + e
__global__ __launch_bounds__(256)
void perm_h_kernel(const float* __restrict__ hr, const float* __restrict__ hi,
                   unsigned short* __restrict__ ws)
{
  const int blk   = blockIdx.x;        // b2m*8 + kt  (512 blocks)
  const int kt    = blk & 7;
  const int b2m   = blk >> 3;
  const int plane = threadIdx.x >> 7;  // 0..1
  const int row   = threadIdx.x & 127; // 0..127
  const int b     = b2m >> 1;
  const int bm    = b2m & 1;

  const float* src = (plane ? hi : hr)
      + ((size_t)b * NC + bm * 128 + row) * NC + kt * 32;
  unsigned short* dst = ws + ((size_t)(b2m * 8 + kt) * 2 + plane) * 4096 + row * 8;

  #pragma unroll
  for (int fq = 0; fq < 4; ++fq) {
    const float4 v0 = *reinterpret_cast<const float4*>(src + fq * 8);
    const float4 v1 = *reinterpret_cast<const float4*>(src + fq * 8 + 4);
    union { uint4 v; unsigned short u[8]; } o;
    o.u[0] = bfr(v0.x); o.u[1] = bfr(v0.y); o.u[2] = bfr(v0.z); o.u[3] = bfr(v0.w);
    o.u[4] = bfr(v1.x); o.u[5] = bfr(v1.y); o.u[6] = bfr(v1.z); o.u[7] = bfr(v1.w);
    *reinterpret_cast<uint4*>(dst + fq * 1024) = o.v;
  }
}

// x LDS: fp32 [k 0..31][p 0..63] per buffer, phys 16B-chunk = logical ^
// swz(k>>3) (0 bank conflicts, verified r2-r11). H LDS: bf16 [fq][row][8]
// (2-way = free). Pipeline: depth-2, ONE barrier/iter.
// Counted-vmcnt barrier (PRE=1): per-wave FIFO per iter = stage(t+1)[3] then
// noise(t)[4]. At wait before barrier(t): queue = stage(t)[3] | noise(t-1)[4]
// -> vmcnt(4) retires exactly stage(t); noise floats to its epilogue use.
// t==0: vmcnt(0) (only stage(0) outstanding). Ordering per r5: own-wait
// BEFORE s_barrier => all waves' stage(t) landed when any wave proceeds.
// LDS reuse safe: iter t-1 ds_reads are consumed by MFMAs (lgkmcnt) before a
// wave reaches barrier(t); stage(t+1) writes the other buffer post-barrier.
template<int PRE>
__global__ __launch_bounds__(512, 4)
void rayleigh_main(const float* __restrict__ xg,
                   const float* __restrict__ Hrg,
                   const float* __restrict__ Hig,
                   const unsigned short* __restrict__ Hperm,
                   const float* __restrict__ nrg,
                   const float* __restrict__ nig,
                   float* __restrict__ outg)
{
  __shared__ float x_lds[2][BK * BN];            // 2 x 8KB
  __shared__ unsigned short hr_lds[2][4096];     // 2 x 8KB  [fq][row][8]
  __shared__ unsigned short hi_lds[2][4096];     // 2 x 8KB

  // XCD-chunked bijection: 3136 = 8*392. Each XCD owns 4 whole batches.
  const int raw = blockIdx.x;
  const int v   = (raw & 7) * 392 + (raw >> 3);
  const int b   = v / 98;
  const int r2  = v - b * 98;
  const int bm  = r2 / 49;
  const int bn  = r2 - bm * 49;

  const int tid  = threadIdx.x;
  const int lane = tid & 63;
  const int wave = tid >> 6;      // 8 waves: 2(M) x 4(N)
  const int wm   = wave >> 2;
  const int wn   = wave & 3;
  const int fr   = lane & 15;
  const int fq   = lane >> 4;

  const float* xsrc = xg + (size_t)b * NC * NP + (size_t)bn * BN;
  const size_t hrowbase = (size_t)b * NC + bm * BM;
  const size_t hpbase   = (size_t)((b * 2 + bm) * 8);

  // stage one K-tile into buffer `buf`: x 8KB (wave w -> chunk w) + H 16KB
  // (wave w -> 2 contiguous 1KB chunks from permuted ws). 3 vmem ops/wave.
  auto stage = [&](int t, int buf) {
    {
      const int C16 = wave * 64 + lane;          // 16B chunk idx in 8KB x-tile
      const int k   = C16 >> 4;
      const int cp  = C16 & 15;
      const int fqk = k >> 3;
      const int cl  = cp ^ (((fqk & 1) << 2) | (fqk >> 1));
      const float* src = xsrc + (size_t)(t * BK + k) * NP + cl * 4;
      gload16(src, (char*)x_lds[buf] + wave * 1024);
    }
    if constexpr (PRE) {
      #pragma unroll
      for (int i = 0; i < 2; ++i) {
        const int c     = wave * 2 + i;          // 0..15
        const int plane = c >> 3;                // 0=r, 1=i
        const int fqc   = (c >> 1) & 3;
        const int half  = c & 1;
        unsigned short* hl = plane ? hi_lds[buf] : hr_lds[buf];
        const unsigned short* src = Hperm
            + ((hpbase + t) * 2 + plane) * 4096
            + fqc * 1024 + (half * 64 + lane) * 8;   // contiguous per lane
        gload16(src, (char*)hl + fqc * 2048 + half * 1024);
      }
    }
  };

  f32x4 accR[4], accI[4];
  #pragma unroll
  for (int m = 0; m < 4; ++m) {
    accR[m] = (f32x4){0.f, 0.f, 0.f, 0.f};
    accI[m] = (f32x4){0.f, 0.f, 0.f, 0.f};
  }
  float nrv[4][4], niv[4][4];

  const size_t obase = ((size_t)b * NC + bm * BM + wm * 64 + fq * 4) * NP
                     + (size_t)bn * BN + wn * 16 + fr;
  const int xork = ((fq & 1) << 6) | ((fq >> 1) << 4);
  const int pcol = ((wn * 16 + fr) << 2) ^ xork;

  stage(0, 0);

  #pragma unroll
  for (int t = 0; t < NKI; ++t) {
    if constexpr (PRE) {
      // counted wait: retire exactly stage(t); noise(t-1) stays in flight
      if (t == 0) asm volatile("s_waitcnt vmcnt(0)" ::: "memory");
      else        asm volatile("s_waitcnt vmcnt(4)" ::: "memory");
      __builtin_amdgcn_s_barrier();
      __builtin_amdgcn_sched_barrier(0);   // rule #18: no LDS-read hoisting
    } else {
      __syncthreads();
    }
    if (t + 1 < NKI) stage(t + 1, (t + 1) & 1);

    // noise prefetch chunk t: 4 NT dword loads -> regs, used ONLY in epilogue
    {
      const int m = t >> 1, rb = (t & 1) * 2;
      #pragma unroll
      for (int r = 0; r < 2; ++r) {
        const size_t idx = obase + (size_t)(m * 16 + rb + r) * NP;
        nrv[m][rb + r] = __builtin_nontemporal_load(nrg + idx);
        niv[m][rb + r] = __builtin_nontemporal_load(nig + idx);
      }
    }

    // B-fragment: 8 swizzled ds_read_b32 + pk-convert (0 bank conflicts)
    const char* xbuf = (const char*)x_lds[t & 1];
    union { short8 s; unsigned short u[8]; } u;
    #pragma unroll
    for (int j = 0; j < 8; ++j) {
      const float f = *reinterpret_cast<const float*>(xbuf + ((fq * 8 + j) << 8) + pcol);
      u.u[j] = bfr(f);
    }
    const short8 xb = u.s;

    // A-fragments from LDS (ds_read_b128, 2-way = free) + MFMA
    #pragma unroll
    for (int m = 0; m < 4; ++m) {
      const int row = wm * 64 + m * 16 + fr;
      short8 ar, ai;
      if constexpr (PRE) {
        ar = *reinterpret_cast<const short8*>(&hr_lds[t & 1][fq * 1024 + row * 8]);
        ai = *reinterpret_cast<const short8*>(&hi_lds[t & 1][fq * 1024 + row * 8]);
      } else {
        const float* p1 = Hrg + (hrowbase + row) * NC + t * 32 + fq * 8;
        const float* p2 = Hig + (hrowbase + row) * NC + t * 32 + fq * 8;
        const float4 v0 = *reinterpret_cast<const float4*>(p1);
        const float4 v1 = *reinterpret_cast<const float4*>(p1 + 4);
        const float4 w0 = *reinterpret_cast<const float4*>(p2);
        const float4 w1 = *reinterpret_cast<const float4*>(p2 + 4);
        union { short8 s; unsigned short uu[8]; } a1, a2;
        a1.uu[0] = bfr(v0.x); a1.uu[1] = bfr(v0.y); a1.uu[2] = bfr(v0.z); a1.uu[3] = bfr(v0.w);
        a1.uu[4] = bfr(v1.x); a1.uu[5] = bfr(v1.y); a1.uu[6] = bfr(v1.z); a1.uu[7] = bfr(v1.w);
        a2.uu[0] = bfr(w0.x); a2.uu[1] = bfr(w0.y); a2.uu[2] = bfr(w0.z); a2.uu[3] = bfr(w0.w);
        a2.uu[4] = bfr(w1.x); a2.uu[5] = bfr(w1.y); a2.uu[6] = bfr(w1.z); a2.uu[7] = bfr(w1.w);
        ar = a1.s; ai = a2.s;
      }
      accR[m] = __builtin_amdgcn_mfma_f32_16x16x32_bf16(ar, xb, accR[m], 0, 0, 0);
      accI[m] = __builtin_amdgcn_mfma_f32_16x16x32_bf16(ai, xb, accI[m], 0, 0, 0);
    }
  }

  // ---- epilogue: pure compute + store (noise already in regs; compiler
  //      inserts the vmcnt waits for the noise registers' first use) ----
  const float scale = 0.04419417382415922f;  // 1/sqrt(512)
  const float nstd  = 0.01f;
  #pragma unroll
  for (int m = 0; m < 4; ++m)
    #pragma unroll
    for (int r = 0; r < 4; ++r) {
      const size_t idx = obase + (size_t)(m * 16 + r) * NP;
      const float yr = accR[m][r] * scale + nrv[m][r] * nstd;
      const float yi = accI[m][r] * scale + niv[m][r] * nstd;
      outg[idx] = sqrtf(yr * yr + yi * yi);
    }
}

extern "C" void kernel_launch(void* const* d_in, const int* in_sizes, int n_in,
                              void* d_out, int out_size, void* d_ws, size_t ws_size,
                              hipStream_t stream) {
  const float* x  = (const float*)d_in[0];
  const float* Hr = (const float*)d_in[1];
  const float* Hi = (const float*)d_in[2];
  const float* nr = (const float*)d_in[3];
  const float* ni = (const float*)d_in[4];
  float* out = (float*)d_out;

  const size_t HN = (size_t)NBATCH * NC * NC;  // 2,097,152 elems per H array

  if (ws_size >= HN * 2 * sizeof(unsigned short)) {
    unsigned short* hperm = (unsigned short*)d_ws;
    hipLaunchKernelGGL(perm_h_kernel, dim3(512), dim3(256), 0, stream, Hr, Hi, hperm);
    hipLaunchKernelGGL((rayleigh_main<1>), dim3(NBATCH * 2 * NBN), dim3(512), 0, stream,
                       x, Hr, Hi, hperm, nr, ni, out);
  } else {
    hipLaunchKernelGGL((rayleigh_main<0>), dim3(NBATCH * 2 * NBN), dim3(512), 0, stream,
                       x, Hr, Hi, (const unsigned short*)nullptr, nr, ni, out);
  }
}